// Round 2
// baseline (2167.752 us; speedup 1.0000x reference)
//
#include <hip/hip_runtime.h>
#include <hip/hip_bf16.h>

#define DEV static __device__ __forceinline__

typedef short s16x8 __attribute__((ext_vector_type(8)));
typedef float f32x4 __attribute__((ext_vector_type(4)));
typedef unsigned short u16;

constexpr int Bn = 64, Pn = 196, ENCn = 2048, EMBn = 512, DECn = 512, ATTn = 512;
constexpr int VOCABn = 10000, Sn = 20;

DEV u16 f2bf(float x) {
  union { float f; unsigned u; } v; v.f = x;
  unsigned r = v.u + 0x7fffu + ((v.u >> 16) & 1u);
  return (u16)(r >> 16);
}
DEV float bf2f(u16 b) {
  union { unsigned u; float f; } v; v.u = ((unsigned)b) << 16;
  return v.f;
}
DEV float sigm(float x) { return 1.f / (1.f + __expf(-x)); }
DEV float tanh_fast(float x) {
  // 1 - 2/(e^{2x}+1): exact at +-inf, v_exp-based, ~ulp-accurate vs tanhf
  float e = __expf(2.f * x);
  return 1.f - 2.f / (e + 1.f);
}

DEV s16x8 ld8(const u16* p) { return *reinterpret_cast<const s16x8*>(p); }
DEV s16x8 ld8(const float* p) {
  s16x8 r;
#pragma unroll
  for (int j = 0; j < 8; j++) r[j] = (short)f2bf(p[j]);
  return r;
}
DEV f32x4 mfma(s16x8 a, s16x8 b, f32x4 c) {
  return __builtin_amdgcn_mfma_f32_16x16x32_bf16(a, b, c, 0, 0, 0);
}

#define GLOAD_LDS16(gsrc, ldst)                                                \
  __builtin_amdgcn_global_load_lds(                                            \
      (const __attribute__((address_space(1))) void*)(gsrc),                   \
      (__attribute__((address_space(3))) void*)(ldst), 16, 0, 0)

// ---------------- conversion f32 -> bf16, 8 elements/thread ----------------
__global__ void k_cvt8(const float* __restrict__ src, u16* __restrict__ dst, int n8) {
  int i = blockIdx.x * 256 + threadIdx.x;
  int stride = gridDim.x * 256;
  for (; i < n8; i += stride) {
    const float4* s = (const float4*)(src + (size_t)i * 8);
    float4 a = s[0], b = s[1];
    s16x8 o;
    o[0] = (short)f2bf(a.x); o[1] = (short)f2bf(a.y);
    o[2] = (short)f2bf(a.z); o[3] = (short)f2bf(a.w);
    o[4] = (short)f2bf(b.x); o[5] = (short)f2bf(b.y);
    o[6] = (short)f2bf(b.z); o[7] = (short)f2bf(b.w);
    *(s16x8*)(dst + (size_t)i * 8) = o;
  }
}

// ---------------- mean over P ----------------
__global__ void k_avg(const float* __restrict__ feat, float* __restrict__ avg) {
  int idx = blockIdx.x * 256 + threadIdx.x;   // B*ENC = 131072
  int b = idx >> 11, e = idx & 2047;
  const float* p = feat + (size_t)b * Pn * ENCn + e;
  float s = 0.f;
  for (int k = 0; k < Pn; k++) s += p[(size_t)k * ENCn];
  avg[idx] = s * (1.0f / 196.0f);
}

// ---------------- generic skinny GEMM: C[64,N] = act(A[64,K] @ W[N,K]^T + b) ----
template<typename TA, typename TW, int ACT, int K>
__global__ __launch_bounds__(256) void k_lin64(
    const TA* __restrict__ A, const TW* __restrict__ W,
    const float* __restrict__ bias1,
    float* __restrict__ outF, size_t ldo, u16* __restrict__ outB) {
  int wid = threadIdx.x >> 6, lane = threadIdx.x & 63;
  int r = lane & 15, hi = lane >> 4;
  int n0 = blockIdx.x * 16;
  const TA* ap = A + (size_t)(wid * 16 + r) * K + hi * 8;
  const TW* wp = W + (size_t)(n0 + r) * K + hi * 8;
  f32x4 acc = {0.f, 0.f, 0.f, 0.f};
  for (int k = 0; k < K; k += 32) acc = mfma(ld8(ap + k), ld8(wp + k), acc);
  int col = n0 + r;
  float bb = bias1 ? bias1[col] : 0.f;
#pragma unroll
  for (int j = 0; j < 4; j++) {
    int row = wid * 16 + hi * 4 + j;
    float v = acc[j] + bb;
    if (ACT) v = fmaxf(v, 0.f);
    if (outF) outF[(size_t)row * ldo + col] = v;
    if (outB) outB[(size_t)row * DECn + col] = f2bf(v);
  }
}

// ---------------- enc_proj: m97-style 128x128 tile, BK=32, global_load_lds ----
// grid (4, 98): n-tiles x m-tiles. 256 thr = 4 waves in 2x2, each 64x64 out.
__global__ __launch_bounds__(256) void k_encproj(
    const u16* __restrict__ Abf, const u16* __restrict__ Wbf,
    const float* __restrict__ bias, float* __restrict__ out) {
  __shared__ u16 As[128][32];
  __shared__ u16 Bs[128][32];
  int tid = threadIdx.x;
  int wid = tid >> 6, lane = tid & 63, r = lane & 15, hi = lane >> 4;
  int wm = wid >> 1, wn = wid & 1;
  int m0 = blockIdx.y * 128, n0 = blockIdx.x * 128;
  int srow = tid >> 2, scol = (tid & 3) * 8;   // staging row/col (per round r: +64 rows)
  const u16* ga = Abf + (size_t)(m0 + srow) * ENCn + scol;
  const u16* gb = Wbf + (size_t)(n0 + srow) * ENCn + scol;
  u16* As1 = &As[0][0];
  u16* Bs1 = &Bs[0][0];
  f32x4 acc[4][4] = {};
  for (int k0 = 0; k0 < ENCn; k0 += 32) {
    // stage 128x32 A and B: 2 rounds each, 16B per thread per round
    GLOAD_LDS16(ga + k0,                      As1 + wid * 512);
    GLOAD_LDS16(ga + k0 + (size_t)64 * ENCn,  As1 + 2048 + wid * 512);
    GLOAD_LDS16(gb + k0,                      Bs1 + wid * 512);
    GLOAD_LDS16(gb + k0 + (size_t)64 * ENCn,  Bs1 + 2048 + wid * 512);
    __syncthreads();
    s16x8 af[4], bfr[4];
#pragma unroll
    for (int i = 0; i < 4; i++) af[i]  = *(const s16x8*)(As1 + (wm * 64 + i * 16 + r) * 32 + hi * 8);
#pragma unroll
    for (int j = 0; j < 4; j++) bfr[j] = *(const s16x8*)(Bs1 + (wn * 64 + j * 16 + r) * 32 + hi * 8);
#pragma unroll
    for (int i = 0; i < 4; i++)
#pragma unroll
      for (int j = 0; j < 4; j++)
        acc[i][j] = mfma(af[i], bfr[j], acc[i][j]);
    __syncthreads();
  }
#pragma unroll
  for (int i = 0; i < 4; i++)
#pragma unroll
    for (int j = 0; j < 4; j++) {
      int col = n0 + wn * 64 + j * 16 + r;
      float bb = bias[col];
#pragma unroll
      for (int q = 0; q < 4; q++) {
        int row = m0 + wm * 64 + i * 16 + hi * 4 + q;
        out[(size_t)row * 512 + col] = acc[i][j][q] + bb;
      }
    }
}

// ---------------- attention scores: 4 p per wave, decp/Vw register-resident ---
// grid (13, 64), 256 thr = 4 waves.
__global__ __launch_bounds__(256) void k_attn(
    const float* __restrict__ encp, const float* __restrict__ decp,
    const float* __restrict__ Vw, const float* __restrict__ Vb,
    float* __restrict__ e) {
  int wid = threadIdx.x >> 6, lane = threadIdx.x & 63;
  int b = blockIdx.y;
  int p0 = (blockIdx.x * 4 + wid) * 4;
  const float* dp = decp + (size_t)b * ATTn + lane * 8;
  float4 dv0 = *(const float4*)dp, dv1 = *(const float4*)(dp + 4);
  float4 vv0 = *(const float4*)(Vw + lane * 8), vv1 = *(const float4*)(Vw + lane * 8 + 4);
  float s[4] = {0.f, 0.f, 0.f, 0.f};
#pragma unroll
  for (int pp = 0; pp < 4; pp++) {
    int p = p0 + pp;
    if (p < Pn) {
      const float* ep = encp + ((size_t)b * Pn + p) * ATTn + lane * 8;
      float4 e0 = *(const float4*)ep, e1 = *(const float4*)(ep + 4);
      float t = 0.f;
      t += vv0.x * tanh_fast(e0.x + dv0.x);
      t += vv0.y * tanh_fast(e0.y + dv0.y);
      t += vv0.z * tanh_fast(e0.z + dv0.z);
      t += vv0.w * tanh_fast(e0.w + dv0.w);
      t += vv1.x * tanh_fast(e1.x + dv1.x);
      t += vv1.y * tanh_fast(e1.y + dv1.y);
      t += vv1.z * tanh_fast(e1.z + dv1.z);
      t += vv1.w * tanh_fast(e1.w + dv1.w);
      s[pp] = t;
    }
  }
#pragma unroll
  for (int pp = 0; pp < 4; pp++) {
    float t = s[pp];
    for (int m = 32; m; m >>= 1) t += __shfl_xor(t, m);
    if (lane == 0 && p0 + pp < Pn) e[(size_t)b * Pn + p0 + pp] = t + Vb[0];
  }
}

// ---------------- softmax (recomputed per block) + ctx chunk -> bf16 ----------
__global__ __launch_bounds__(256) void k_ctx(
    const float* __restrict__ e, const u16* __restrict__ featbf,
    u16* __restrict__ ctxbf) {
  __shared__ float sw[Pn];
  __shared__ float red[256];
  int b = blockIdx.y, chunk = blockIdx.x, tid = threadIdx.x;
  float ev = (tid < Pn) ? e[(size_t)b * Pn + tid] : -3.0e38f;
  red[tid] = ev; __syncthreads();
  for (int s = 128; s > 0; s >>= 1) { if (tid < s) red[tid] = fmaxf(red[tid], red[tid + s]); __syncthreads(); }
  float m = red[0]; __syncthreads();
  float ex = (tid < Pn) ? __expf(ev - m) : 0.f;
  red[tid] = ex; __syncthreads();
  for (int s = 128; s > 0; s >>= 1) { if (tid < s) red[tid] += red[tid + s]; __syncthreads(); }
  float inv = 1.f / red[0];
  if (tid < Pn) sw[tid] = ex * inv;
  __syncthreads();
  int e0 = chunk * 512 + tid * 2;
  float ax = 0.f, ay = 0.f;
  const u16* fp = featbf + (size_t)b * Pn * ENCn + e0;
#pragma unroll 4
  for (int p = 0; p < Pn; p++) {
    float w = sw[p];
    unsigned v = *(const unsigned*)(fp + (size_t)p * ENCn);
    ax += w * bf2f((u16)(v & 0xffffu));
    ay += w * bf2f((u16)(v >> 16));
  }
  unsigned pk = (unsigned)f2bf(ax) | ((unsigned)f2bf(ay) << 16);
  *(unsigned*)(ctxbf + (size_t)b * ENCn + e0) = pk;
}

// ---------------- fused gates GEMM + LSTM pointwise ---------------------------
// grid 32 blocks (16 LSTM dims each), 256 thr = 4 waves (m-tiles of b).
// Each wave holds 4 independent accumulators (i,f,g,o) for the same 16 dims.
__global__ __launch_bounds__(256) void k_gates_lstm(
    const u16* __restrict__ ctxbf, const float* __restrict__ embw,
    const int* __restrict__ caps, int t, const u16* __restrict__ hin,
    const u16* __restrict__ Wih, const u16* __restrict__ Whh,
    const float* __restrict__ bih, const float* __restrict__ bhh,
    float* __restrict__ c, u16* __restrict__ hout) {
  int wid = threadIdx.x >> 6, lane = threadIdx.x & 63;
  int r = lane & 15, hi = lane >> 4;
  int d0 = blockIdx.x * 16;
  int brow = wid * 16 + r;
  f32x4 acc[4] = {};
  const u16* w0 = Wih + (size_t)(0 * 512 + d0 + r) * 2560 + hi * 8;
  const u16* w1 = Wih + (size_t)(1 * 512 + d0 + r) * 2560 + hi * 8;
  const u16* w2 = Wih + (size_t)(2 * 512 + d0 + r) * 2560 + hi * 8;
  const u16* w3 = Wih + (size_t)(3 * 512 + d0 + r) * 2560 + hi * 8;
  // ctx segment (K = 2048)
  const u16* arow = ctxbf + (size_t)brow * ENCn + hi * 8;
  for (int k = 0; k < 2048; k += 32) {
    s16x8 a = ld8(arow + k);
    acc[0] = mfma(a, ld8(w0 + k), acc[0]);
    acc[1] = mfma(a, ld8(w1 + k), acc[1]);
    acc[2] = mfma(a, ld8(w2 + k), acc[2]);
    acc[3] = mfma(a, ld8(w3 + k), acc[3]);
  }
  // embedding segment (K = 512), f32 rows converted on the fly
  int id = caps[brow * Sn + t];
  const float* erow = embw + (size_t)id * EMBn + hi * 8;
  for (int k = 0; k < 512; k += 32) {
    s16x8 a = ld8(erow + k);
    acc[0] = mfma(a, ld8(w0 + 2048 + k), acc[0]);
    acc[1] = mfma(a, ld8(w1 + 2048 + k), acc[1]);
    acc[2] = mfma(a, ld8(w2 + 2048 + k), acc[2]);
    acc[3] = mfma(a, ld8(w3 + 2048 + k), acc[3]);
  }
  // h segment (K = 512)
  const u16* hrow = hin + (size_t)brow * DECn + hi * 8;
  const u16* v0 = Whh + (size_t)(0 * 512 + d0 + r) * 512 + hi * 8;
  const u16* v1 = Whh + (size_t)(1 * 512 + d0 + r) * 512 + hi * 8;
  const u16* v2 = Whh + (size_t)(2 * 512 + d0 + r) * 512 + hi * 8;
  const u16* v3 = Whh + (size_t)(3 * 512 + d0 + r) * 512 + hi * 8;
  for (int k = 0; k < 512; k += 32) {
    s16x8 a = ld8(hrow + k);
    acc[0] = mfma(a, ld8(v0 + k), acc[0]);
    acc[1] = mfma(a, ld8(v1 + k), acc[1]);
    acc[2] = mfma(a, ld8(v2 + k), acc[2]);
    acc[3] = mfma(a, ld8(v3 + k), acc[3]);
  }
  int col = d0 + r;
  float b0 = bih[0 * 512 + col] + bhh[0 * 512 + col];
  float b1 = bih[1 * 512 + col] + bhh[1 * 512 + col];
  float b2 = bih[2 * 512 + col] + bhh[2 * 512 + col];
  float b3 = bih[3 * 512 + col] + bhh[3 * 512 + col];
#pragma unroll
  for (int j = 0; j < 4; j++) {
    int row = wid * 16 + hi * 4 + j;
    float gi = acc[0][j] + b0, gf = acc[1][j] + b1;
    float gg = acc[2][j] + b2, go = acc[3][j] + b3;
    size_t ci = (size_t)row * DECn + col;
    float cn = sigm(gf) * c[ci] + sigm(gi) * tanh_fast(gg);
    float hn = sigm(go) * tanh_fast(cn);
    c[ci] = cn;
    hout[ci] = f2bf(hn);
  }
}

// ---------------- fused h consumers: logits (blocks 0..624) + dec_proj (625..656)
__global__ __launch_bounds__(256) void k_hout(
    const u16* __restrict__ h, const u16* __restrict__ fcw,
    const float* __restrict__ fc_b, float* __restrict__ outt,
    const u16* __restrict__ wdec, const float* __restrict__ wdec_b,
    float* __restrict__ decp) {
  int wid = threadIdx.x >> 6, lane = threadIdx.x & 63;
  int r = lane & 15, hi = lane >> 4;
  bool dec = blockIdx.x >= 625;
  int n0 = (dec ? (int)blockIdx.x - 625 : (int)blockIdx.x) * 16;
  const u16* W = (dec ? wdec : fcw) + (size_t)(n0 + r) * 512 + hi * 8;
  const u16* ap = h + (size_t)(wid * 16 + r) * 512 + hi * 8;
  f32x4 acc = {0.f, 0.f, 0.f, 0.f};
  for (int k = 0; k < 512; k += 32) acc = mfma(ld8(ap + k), ld8(W + k), acc);
  int col = n0 + r;
  float bb = dec ? wdec_b[col] : fc_b[col];
  float* o = dec ? decp : outt;
  size_t ldo = dec ? (size_t)512 : (size_t)Sn * VOCABn;
#pragma unroll
  for (int j = 0; j < 4; j++) {
    int row = wid * 16 + hi * 4 + j;
    o[(size_t)row * ldo + col] = acc[j] + bb;
  }
}

// ============================================================================
extern "C" void kernel_launch(void* const* d_in, const int* in_sizes, int n_in,
                              void* d_out, int out_size, void* d_ws, size_t ws_size,
                              hipStream_t stream) {
  const float* image_feat = (const float*)d_in[0];
  const int*   captions   = (const int*)d_in[1];
  const float* wenc_w = (const float*)d_in[2];
  const float* wenc_b = (const float*)d_in[3];
  const float* wdec_w = (const float*)d_in[4];
  const float* wdec_b = (const float*)d_in[5];
  const float* V_w    = (const float*)d_in[6];
  const float* V_b    = (const float*)d_in[7];
  const float* embed_w = (const float*)d_in[8];
  const float* h0_w = (const float*)d_in[9];
  const float* h0_b = (const float*)d_in[10];
  const float* c0_w = (const float*)d_in[11];
  const float* c0_b = (const float*)d_in[12];
  const float* W_ih = (const float*)d_in[13];
  const float* b_ih = (const float*)d_in[14];
  const float* W_hh = (const float*)d_in[15];
  const float* b_hh = (const float*)d_in[16];
  const float* fc_w = (const float*)d_in[17];
  const float* fc_b = (const float*)d_in[18];
  float* out = (float*)d_out;

  char* w = (char*)d_ws;
  auto alloc = [&](size_t bytes) { void* p = (void*)w; w += (bytes + 255) & ~(size_t)255; return p; };
  u16* if_bf   = (u16*)alloc(sizeof(u16) * (size_t)Bn * Pn * ENCn);
  u16* wenc_bf = (u16*)alloc(sizeof(u16) * (size_t)ATTn * ENCn);
  u16* wdec_bf = (u16*)alloc(sizeof(u16) * (size_t)ATTn * DECn);
  u16* Wih_bf  = (u16*)alloc(sizeof(u16) * (size_t)2048 * 2560);
  u16* Whh_bf  = (u16*)alloc(sizeof(u16) * (size_t)2048 * 512);
  u16* fcw_bf  = (u16*)alloc(sizeof(u16) * (size_t)VOCABn * DECn);
  u16* h_a     = (u16*)alloc(sizeof(u16) * (size_t)Bn * DECn);
  u16* h_b     = (u16*)alloc(sizeof(u16) * (size_t)Bn * DECn);
  u16* ctx_bf  = (u16*)alloc(sizeof(u16) * (size_t)Bn * ENCn);
  float* avg   = (float*)alloc(sizeof(float) * (size_t)Bn * ENCn);
  float* encp  = (float*)alloc(sizeof(float) * (size_t)Bn * Pn * ATTn);
  float* decp  = (float*)alloc(sizeof(float) * (size_t)Bn * ATTn);
  float* evec  = (float*)alloc(sizeof(float) * (size_t)Bn * Pn);
  float* cbuf  = (float*)alloc(sizeof(float) * (size_t)Bn * DECn);

  auto cvt = [&](const float* s, u16* d, size_t n) {
    int n8 = (int)(n / 8);
    int blocks = (n8 + 255) / 256; if (blocks > 2048) blocks = 2048;
    k_cvt8<<<blocks, 256, 0, stream>>>(s, d, n8);
  };
  cvt(image_feat, if_bf, (size_t)Bn * Pn * ENCn);
  cvt(wenc_w, wenc_bf, (size_t)ATTn * ENCn);
  cvt(wdec_w, wdec_bf, (size_t)ATTn * DECn);
  cvt(W_ih, Wih_bf, (size_t)2048 * 2560);
  cvt(W_hh, Whh_bf, (size_t)2048 * 512);
  cvt(fc_w, fcw_bf, (size_t)VOCABn * DECn);

  k_avg<<<512, 256, 0, stream>>>(image_feat, avg);
  k_encproj<<<dim3(4, 98), 256, 0, stream>>>(if_bf, wenc_bf, wenc_b, encp);
  // h0 = relu(avg @ h0_w^T + b) -> bf16; c0 -> f32
  k_lin64<float, float, 1, 2048><<<32, 256, 0, stream>>>(avg, h0_w, h0_b, nullptr, 0, h_a);
  k_lin64<float, float, 1, 2048><<<32, 256, 0, stream>>>(avg, c0_w, c0_b, cbuf, 512, nullptr);
  // dec_proj(h0)
  k_lin64<u16, u16, 0, 512><<<32, 256, 0, stream>>>(h_a, wdec_bf, wdec_b, decp, 512, nullptr);

  for (int t = 0; t < Sn; t++) {
    u16* hin  = (t & 1) ? h_b : h_a;
    u16* hout = (t & 1) ? h_a : h_b;
    k_attn<<<dim3(13, Bn), 256, 0, stream>>>(encp, decp, V_w, V_b, evec);
    k_ctx<<<dim3(4, Bn), 256, 0, stream>>>(evec, if_bf, ctx_bf);
    k_gates_lstm<<<32, 256, 0, stream>>>(ctx_bf, embed_w, captions, t, hin,
                                         Wih_bf, Whh_bf, b_ih, b_hh, cbuf, hout);
    k_hout<<<657, 256, 0, stream>>>(hout, fcw_bf, fc_b, out + (size_t)t * VOCABn,
                                    wdec_bf, wdec_b, decp);
  }
}

// Round 3
// 1347.317 us; speedup vs baseline: 1.6089x; 1.6089x over previous
//
#include <hip/hip_runtime.h>
#include <hip/hip_bf16.h>

#define DEV static __device__ __forceinline__

typedef short s16x8 __attribute__((ext_vector_type(8)));
typedef float f32x4 __attribute__((ext_vector_type(4)));
typedef unsigned short u16;

constexpr int Bn = 64, Pn = 196, ENCn = 2048, EMBn = 512, DECn = 512, ATTn = 512;
constexpr int VOCABn = 10000, Sn = 20;

DEV u16 f2bf(float x) {
  union { float f; unsigned u; } v; v.f = x;
  unsigned r = v.u + 0x7fffu + ((v.u >> 16) & 1u);
  return (u16)(r >> 16);
}
DEV float bf2f(u16 b) {
  union { unsigned u; float f; } v; v.u = ((unsigned)b) << 16;
  return v.f;
}
DEV float sigm(float x) { return 1.f / (1.f + __expf(-x)); }
DEV float tanh_fast(float x) {
  float e = __expf(2.f * x);
  return 1.f - 2.f / (e + 1.f);
}

DEV s16x8 ld8(const u16* p) { return *reinterpret_cast<const s16x8*>(p); }
DEV s16x8 ld8(const float* p) {
  s16x8 r;
#pragma unroll
  for (int j = 0; j < 8; j++) r[j] = (short)f2bf(p[j]);
  return r;
}
DEV f32x4 mfma(s16x8 a, s16x8 b, f32x4 c) {
  return __builtin_amdgcn_mfma_f32_16x16x32_bf16(a, b, c, 0, 0, 0);
}

#define GLOAD_LDS16(gsrc, ldst)                                                \
  __builtin_amdgcn_global_load_lds(                                            \
      (const __attribute__((address_space(1))) void*)(gsrc),                   \
      (__attribute__((address_space(3))) void*)(ldst), 16, 0, 0)

// ---------------- conversion f32 -> bf16, 8 elements/thread ----------------
__global__ void k_cvt8(const float* __restrict__ src, u16* __restrict__ dst, int n8) {
  int i = blockIdx.x * 256 + threadIdx.x;
  int stride = gridDim.x * 256;
  for (; i < n8; i += stride) {
    const float4* s = (const float4*)(src + (size_t)i * 8);
    float4 a = s[0], b = s[1];
    s16x8 o;
    o[0] = (short)f2bf(a.x); o[1] = (short)f2bf(a.y);
    o[2] = (short)f2bf(a.z); o[3] = (short)f2bf(a.w);
    o[4] = (short)f2bf(b.x); o[5] = (short)f2bf(b.y);
    o[6] = (short)f2bf(b.z); o[7] = (short)f2bf(b.w);
    *(s16x8*)(dst + (size_t)i * 8) = o;
  }
}

// ---------------- image_feat cvt fused with mean over P ----------------
// grid (8, 64): 256 enc dims per block, one b. Saves a second 103MB read.
__global__ __launch_bounds__(256) void k_cvtfeat_avg(
    const float* __restrict__ feat, u16* __restrict__ featbf,
    float* __restrict__ avg) {
  int b = blockIdx.y, e = blockIdx.x * 256 + threadIdx.x;
  const float* p = feat + (size_t)b * Pn * ENCn + e;
  u16* q = featbf + (size_t)b * Pn * ENCn + e;
  float s = 0.f;
  for (int k = 0; k < Pn; k++) {
    float v = p[(size_t)k * ENCn];
    s += v;
    q[(size_t)k * ENCn] = f2bf(v);
  }
  avg[b * ENCn + e] = s * (1.0f / 196.0f);
}

// ---------------- generic skinny GEMM: C[64,N] = act(A[64,K] @ W[N,K]^T + b) ----
template<typename TA, typename TW, int ACT, int K>
__global__ __launch_bounds__(256) void k_lin64(
    const TA* __restrict__ A, const TW* __restrict__ W,
    const float* __restrict__ bias1,
    float* __restrict__ outF, size_t ldo, u16* __restrict__ outB) {
  int wid = threadIdx.x >> 6, lane = threadIdx.x & 63;
  int r = lane & 15, hi = lane >> 4;
  int n0 = blockIdx.x * 16;
  const TA* ap = A + (size_t)(wid * 16 + r) * K + hi * 8;
  const TW* wp = W + (size_t)(n0 + r) * K + hi * 8;
  f32x4 acc = {0.f, 0.f, 0.f, 0.f};
  for (int k = 0; k < K; k += 32) acc = mfma(ld8(ap + k), ld8(wp + k), acc);
  int col = n0 + r;
  float bb = bias1 ? bias1[col] : 0.f;
#pragma unroll
  for (int j = 0; j < 4; j++) {
    int row = wid * 16 + hi * 4 + j;
    float v = acc[j] + bb;
    if (ACT) v = fmaxf(v, 0.f);
    if (outF) outF[(size_t)row * ldo + col] = v;
    if (outB) outB[(size_t)row * DECn + col] = f2bf(v);
  }
}

// ---------------- enc_proj: m97-style 128x128 tile, BK=32, global_load_lds ----
__global__ __launch_bounds__(256) void k_encproj(
    const u16* __restrict__ Abf, const u16* __restrict__ Wbf,
    const float* __restrict__ bias, float* __restrict__ out) {
  __shared__ u16 As[128][32];
  __shared__ u16 Bs[128][32];
  int tid = threadIdx.x;
  int wid = tid >> 6, lane = tid & 63, r = lane & 15, hi = lane >> 4;
  int wm = wid >> 1, wn = wid & 1;
  int m0 = blockIdx.y * 128, n0 = blockIdx.x * 128;
  int srow = tid >> 2, scol = (tid & 3) * 8;
  const u16* ga = Abf + (size_t)(m0 + srow) * ENCn + scol;
  const u16* gb = Wbf + (size_t)(n0 + srow) * ENCn + scol;
  u16* As1 = &As[0][0];
  u16* Bs1 = &Bs[0][0];
  f32x4 acc[4][4] = {};
  for (int k0 = 0; k0 < ENCn; k0 += 32) {
    GLOAD_LDS16(ga + k0,                      As1 + wid * 512);
    GLOAD_LDS16(ga + k0 + (size_t)64 * ENCn,  As1 + 2048 + wid * 512);
    GLOAD_LDS16(gb + k0,                      Bs1 + wid * 512);
    GLOAD_LDS16(gb + k0 + (size_t)64 * ENCn,  Bs1 + 2048 + wid * 512);
    __syncthreads();
    s16x8 af[4], bfr[4];
#pragma unroll
    for (int i = 0; i < 4; i++) af[i]  = *(const s16x8*)(As1 + (wm * 64 + i * 16 + r) * 32 + hi * 8);
#pragma unroll
    for (int j = 0; j < 4; j++) bfr[j] = *(const s16x8*)(Bs1 + (wn * 64 + j * 16 + r) * 32 + hi * 8);
#pragma unroll
    for (int i = 0; i < 4; i++)
#pragma unroll
      for (int j = 0; j < 4; j++)
        acc[i][j] = mfma(af[i], bfr[j], acc[i][j]);
    __syncthreads();
  }
#pragma unroll
  for (int i = 0; i < 4; i++)
#pragma unroll
    for (int j = 0; j < 4; j++) {
      int col = n0 + wn * 64 + j * 16 + r;
      float bb = bias[col];
#pragma unroll
      for (int q = 0; q < 4; q++) {
        int row = m0 + wm * 64 + i * 16 + hi * 4 + q;
        out[(size_t)row * 512 + col] = acc[i][j][q] + bb;
      }
    }
}

// ---------------- attention scores: wave per (b,p); grid (49, 64) --------------
__global__ __launch_bounds__(256) void k_attn(
    const float* __restrict__ encp, const float* __restrict__ decp,
    const float* __restrict__ Vw, const float* __restrict__ Vb,
    float* __restrict__ e) {
  int wid = threadIdx.x >> 6, lane = threadIdx.x & 63;
  int p = blockIdx.x * 4 + wid;
  int b = blockIdx.y;
  const float* ep = encp + ((size_t)b * Pn + p) * ATTn;
  const float* dp = decp + (size_t)b * ATTn;
  float s = 0.f;
#pragma unroll
  for (int c = 0; c < 2; c++) {
    int a = c * 256 + lane * 4;
    float4 ev = *(const float4*)(ep + a);
    float4 dv = *(const float4*)(dp + a);
    float4 vv = *(const float4*)(Vw + a);
    s += vv.x * tanh_fast(ev.x + dv.x);
    s += vv.y * tanh_fast(ev.y + dv.y);
    s += vv.z * tanh_fast(ev.z + dv.z);
    s += vv.w * tanh_fast(ev.w + dv.w);
  }
  for (int m = 32; m; m >>= 1) s += __shfl_xor(s, m);
  if (lane == 0) e[(size_t)b * Pn + p] = s + Vb[0];
}

// ---------------- softmax (recomputed per block) + ctx chunk -> bf16 ----------
__global__ __launch_bounds__(256) void k_ctx(
    const float* __restrict__ e, const u16* __restrict__ featbf,
    u16* __restrict__ ctxbf) {
  __shared__ float sw[Pn];
  __shared__ float red[256];
  int b = blockIdx.y, chunk = blockIdx.x, tid = threadIdx.x;
  float ev = (tid < Pn) ? e[(size_t)b * Pn + tid] : -3.0e38f;
  red[tid] = ev; __syncthreads();
  for (int s = 128; s > 0; s >>= 1) { if (tid < s) red[tid] = fmaxf(red[tid], red[tid + s]); __syncthreads(); }
  float m = red[0]; __syncthreads();
  float ex = (tid < Pn) ? __expf(ev - m) : 0.f;
  red[tid] = ex; __syncthreads();
  for (int s = 128; s > 0; s >>= 1) { if (tid < s) red[tid] += red[tid + s]; __syncthreads(); }
  float inv = 1.f / red[0];
  if (tid < Pn) sw[tid] = ex * inv;
  __syncthreads();
  int e0 = chunk * 512 + tid * 2;
  float ax = 0.f, ay = 0.f;
  const u16* fp = featbf + (size_t)b * Pn * ENCn + e0;
#pragma unroll 4
  for (int p = 0; p < Pn; p++) {
    float w = sw[p];
    unsigned v = *(const unsigned*)(fp + (size_t)p * ENCn);
    ax += w * bf2f((u16)(v & 0xffffu));
    ay += w * bf2f((u16)(v >> 16));
  }
  unsigned pk = (unsigned)f2bf(ax) | ((unsigned)f2bf(ay) << 16);
  *(unsigned*)(ctxbf + (size_t)b * ENCn + e0) = pk;
}

// ---------------- gates GEMM, split-K: grid (128 n-blocks, 6 K-slices) --------
// slice 0..3: ctx[:, 512*s : 512*s+512] @ Wih[:, same]
// slice 4   : emb @ Wih[:, 2048:2560]
// slice 5   : h   @ Whh
// partials: part[slice][64][2048] f32
__global__ __launch_bounds__(256) void k_gates_split(
    const u16* __restrict__ ctxbf, const float* __restrict__ embw,
    const int* __restrict__ caps, int t, const u16* __restrict__ hin,
    const u16* __restrict__ Wih, const u16* __restrict__ Whh,
    float* __restrict__ part) {
  int wid = threadIdx.x >> 6, lane = threadIdx.x & 63;
  int r = lane & 15, hi = lane >> 4;
  int n0 = blockIdx.x * 16;
  int sl = blockIdx.y;
  int brow = wid * 16 + r;
  f32x4 acc = {0.f, 0.f, 0.f, 0.f};
  if (sl < 4) {
    const u16* a = ctxbf + (size_t)brow * ENCn + sl * 512 + hi * 8;
    const u16* w = Wih + (size_t)(n0 + r) * 2560 + sl * 512 + hi * 8;
#pragma unroll 4
    for (int k = 0; k < 512; k += 32) acc = mfma(ld8(a + k), ld8(w + k), acc);
  } else if (sl == 4) {
    int id = caps[brow * Sn + t];
    const float* a = embw + (size_t)id * EMBn + hi * 8;
    const u16* w = Wih + (size_t)(n0 + r) * 2560 + 2048 + hi * 8;
#pragma unroll 4
    for (int k = 0; k < 512; k += 32) acc = mfma(ld8(a + k), ld8(w + k), acc);
  } else {
    const u16* a = hin + (size_t)brow * DECn + hi * 8;
    const u16* w = Whh + (size_t)(n0 + r) * 512 + hi * 8;
#pragma unroll 4
    for (int k = 0; k < 512; k += 32) acc = mfma(ld8(a + k), ld8(w + k), acc);
  }
#pragma unroll
  for (int j = 0; j < 4; j++) {
    int row = wid * 16 + hi * 4 + j;
    part[((size_t)sl * 64 + row) * 2048 + n0 + r] = acc[j];
  }
}

// ---------------- partial reduce + LSTM pointwise -----------------------------
// grid 128 blocks x 256 thr: idx over 64*512.
__global__ __launch_bounds__(256) void k_lstm_pw(
    const float* __restrict__ part, const float* __restrict__ bih,
    const float* __restrict__ bhh, float* __restrict__ c,
    u16* __restrict__ hout) {
  int idx = blockIdx.x * 256 + threadIdx.x;
  int row = idx >> 9, d = idx & 511;
  float g[4];
#pragma unroll
  for (int gi = 0; gi < 4; gi++) {
    int col = gi * 512 + d;
    float s = bih[col] + bhh[col];
#pragma unroll
    for (int sl = 0; sl < 6; sl++) s += part[((size_t)sl * 64 + row) * 2048 + col];
    g[gi] = s;
  }
  size_t ci = (size_t)row * DECn + d;
  float cn = sigm(g[1]) * c[ci] + sigm(g[0]) * tanh_fast(g[2]);
  float hn = sigm(g[3]) * tanh_fast(cn);
  c[ci] = cn;
  hout[ci] = f2bf(hn);
}

// ---------------- fused h consumers: logits (blocks 0..624) + dec_proj (625..656)
__global__ __launch_bounds__(256) void k_hout(
    const u16* __restrict__ h, const u16* __restrict__ fcw,
    const float* __restrict__ fc_b, float* __restrict__ outt,
    const u16* __restrict__ wdec, const float* __restrict__ wdec_b,
    float* __restrict__ decp) {
  int wid = threadIdx.x >> 6, lane = threadIdx.x & 63;
  int r = lane & 15, hi = lane >> 4;
  bool dec = blockIdx.x >= 625;
  int n0 = (dec ? (int)blockIdx.x - 625 : (int)blockIdx.x) * 16;
  const u16* W = (dec ? wdec : fcw) + (size_t)(n0 + r) * 512 + hi * 8;
  const u16* ap = h + (size_t)(wid * 16 + r) * 512 + hi * 8;
  f32x4 acc = {0.f, 0.f, 0.f, 0.f};
  for (int k = 0; k < 512; k += 32) acc = mfma(ld8(ap + k), ld8(W + k), acc);
  int col = n0 + r;
  float bb = dec ? wdec_b[col] : fc_b[col];
  float* o = dec ? decp : outt;
  size_t ldo = dec ? (size_t)512 : (size_t)Sn * VOCABn;
#pragma unroll
  for (int j = 0; j < 4; j++) {
    int row = wid * 16 + hi * 4 + j;
    o[(size_t)row * ldo + col] = acc[j] + bb;
  }
}

// ============================================================================
extern "C" void kernel_launch(void* const* d_in, const int* in_sizes, int n_in,
                              void* d_out, int out_size, void* d_ws, size_t ws_size,
                              hipStream_t stream) {
  const float* image_feat = (const float*)d_in[0];
  const int*   captions   = (const int*)d_in[1];
  const float* wenc_w = (const float*)d_in[2];
  const float* wenc_b = (const float*)d_in[3];
  const float* wdec_w = (const float*)d_in[4];
  const float* wdec_b = (const float*)d_in[5];
  const float* V_w    = (const float*)d_in[6];
  const float* V_b    = (const float*)d_in[7];
  const float* embed_w = (const float*)d_in[8];
  const float* h0_w = (const float*)d_in[9];
  const float* h0_b = (const float*)d_in[10];
  const float* c0_w = (const float*)d_in[11];
  const float* c0_b = (const float*)d_in[12];
  const float* W_ih = (const float*)d_in[13];
  const float* b_ih = (const float*)d_in[14];
  const float* W_hh = (const float*)d_in[15];
  const float* b_hh = (const float*)d_in[16];
  const float* fc_w = (const float*)d_in[17];
  const float* fc_b = (const float*)d_in[18];
  float* out = (float*)d_out;

  char* w = (char*)d_ws;
  auto alloc = [&](size_t bytes) { void* p = (void*)w; w += (bytes + 255) & ~(size_t)255; return p; };
  u16* if_bf   = (u16*)alloc(sizeof(u16) * (size_t)Bn * Pn * ENCn);
  u16* wenc_bf = (u16*)alloc(sizeof(u16) * (size_t)ATTn * ENCn);
  u16* wdec_bf = (u16*)alloc(sizeof(u16) * (size_t)ATTn * DECn);
  u16* Wih_bf  = (u16*)alloc(sizeof(u16) * (size_t)2048 * 2560);
  u16* Whh_bf  = (u16*)alloc(sizeof(u16) * (size_t)2048 * 512);
  u16* fcw_bf  = (u16*)alloc(sizeof(u16) * (size_t)VOCABn * DECn);
  u16* h_a     = (u16*)alloc(sizeof(u16) * (size_t)Bn * DECn);
  u16* h_b     = (u16*)alloc(sizeof(u16) * (size_t)Bn * DECn);
  u16* ctx_bf  = (u16*)alloc(sizeof(u16) * (size_t)Bn * ENCn);
  float* avg   = (float*)alloc(sizeof(float) * (size_t)Bn * ENCn);
  float* encp  = (float*)alloc(sizeof(float) * (size_t)Bn * Pn * ATTn);
  float* decp  = (float*)alloc(sizeof(float) * (size_t)Bn * ATTn);
  float* evec  = (float*)alloc(sizeof(float) * (size_t)Bn * Pn);
  float* cbuf  = (float*)alloc(sizeof(float) * (size_t)Bn * DECn);
  float* part  = (float*)alloc(sizeof(float) * (size_t)6 * Bn * 2048);

  auto cvt = [&](const float* s, u16* d, size_t n) {
    int n8 = (int)(n / 8);
    int blocks = (n8 + 255) / 256; if (blocks > 2048) blocks = 2048;
    k_cvt8<<<blocks, 256, 0, stream>>>(s, d, n8);
  };
  k_cvtfeat_avg<<<dim3(8, Bn), 256, 0, stream>>>(image_feat, if_bf, avg);
  cvt(wenc_w, wenc_bf, (size_t)ATTn * ENCn);
  cvt(wdec_w, wdec_bf, (size_t)ATTn * DECn);
  cvt(W_ih, Wih_bf, (size_t)2048 * 2560);
  cvt(W_hh, Whh_bf, (size_t)2048 * 512);
  cvt(fc_w, fcw_bf, (size_t)VOCABn * DECn);

  k_encproj<<<dim3(4, 98), 256, 0, stream>>>(if_bf, wenc_bf, wenc_b, encp);
  k_lin64<float, float, 1, 2048><<<32, 256, 0, stream>>>(avg, h0_w, h0_b, nullptr, 0, h_a);
  k_lin64<float, float, 1, 2048><<<32, 256, 0, stream>>>(avg, c0_w, c0_b, cbuf, 512, nullptr);
  k_lin64<u16, u16, 0, 512><<<32, 256, 0, stream>>>(h_a, wdec_bf, wdec_b, decp, 512, nullptr);

  for (int t = 0; t < Sn; t++) {
    u16* hin  = (t & 1) ? h_b : h_a;
    u16* hout = (t & 1) ? h_a : h_b;
    k_attn<<<dim3(49, Bn), 256, 0, stream>>>(encp, decp, V_w, V_b, evec);
    k_ctx<<<dim3(4, Bn), 256, 0, stream>>>(evec, if_bf, ctx_bf);
    k_gates_split<<<dim3(128, 6), 256, 0, stream>>>(ctx_bf, embed_w, captions, t, hin,
                                                    Wih_bf, Whh_bf, part);
    k_lstm_pw<<<128, 256, 0, stream>>>(part, b_ih, b_hh, cbuf, hout);
    k_hout<<<657, 256, 0, stream>>>(hout, fcw_bf, fc_b, out + (size_t)t * VOCABn,
                                    wdec_bf, wdec_b, decp);
  }
}